// Round 1
// baseline (404.947 us; speedup 1.0000x reference)
//
#include <hip/hip_runtime.h>
#include <math.h>

#define BB 16
#define TT 2048
#define DD 1024
#define THRESH 0.95f

// ---------------- Kernel 1: projection + sigmoid + mask ----------------
// alphas[b*T+t] = sigmoid(dot(hs[b,t,:], w) + bias) * hs_mask[b,t]
// One wave (64 lanes) per row; 4 waves / block.
__global__ __launch_bounds__(256) void proj_kernel(
    const float* __restrict__ hs, const float* __restrict__ hs_mask,
    const float* __restrict__ w, const float* __restrict__ bias,
    float* __restrict__ alphas)
{
    int row  = blockIdx.x * 4 + (threadIdx.x >> 6);   // b*T + t
    int lane = threadIdx.x & 63;
    const float4* hp = (const float4*)(hs + (size_t)row * DD);
    const float4* wp = (const float4*)w;
    float sum = 0.f;
#pragma unroll
    for (int j = 0; j < 4; ++j) {
        float4 h4 = hp[lane + 64 * j];
        float4 w4 = wp[lane + 64 * j];
        sum += h4.x * w4.x + h4.y * w4.y + h4.z * w4.z + h4.w * w4.w;
    }
#pragma unroll
    for (int off = 32; off; off >>= 1) sum += __shfl_down(sum, off, 64);
    if (lane == 0) {
        float x  = sum + bias[0];
        float al = 1.f / (1.f + expf(-x));   // expf: <1ulp; __expf too sloppy for fire decisions
        alphas[row] = al * hs_mask[row];
    }
}

// ---------------- Kernel 2: scalar integrate-and-fire scan ----------------
// Per batch b (one block each): serial fp32 chain matching reference order.
// Emits cur[b,t] (coefficient applied to h_t within its segment),
// fire_times[b,r] (t of r-th fire), n_fires[b], len_labels[b]=round(sum alphas).
__global__ __launch_bounds__(256) void scan_kernel(
    const float* __restrict__ alphas, float* __restrict__ cur,
    int* __restrict__ fire_times, int* __restrict__ n_fires,
    int* __restrict__ len_labels)
{
    __shared__ float sa[TT];
    int b = blockIdx.x;
    const float* ap = alphas + (size_t)b * TT;
    for (int t = threadIdx.x; t < TT; t += 256) sa[t] = ap[t];
    __syncthreads();
    if (threadIdx.x == 0) {
        float integ = 0.f;
        int nf = 0;
        double dsum = 0.0;
        float* cp = cur + (size_t)b * TT;
        int*   fp = fire_times + (size_t)b * TT;
        for (int t = 0; t < TT; ++t) {
            float a = sa[t];
            dsum += (double)a;
            float dist = 1.f - integ;      // dist_completion (pre-add integrate)
            integ += a;                    // same fp32 rounding order as reference
            bool fire = integ > THRESH;
            float c = fire ? dist : a;     // cur
            cp[t] = c;
            if (fire) { integ -= 1.f; fp[nf++] = t; }  // subtract exact (Sterbenz)
        }
        n_fires[b]    = nf;
        len_labels[b] = (int)__double2int_rn(dsum);    // round-half-even
    }
}

// ---------------- Kernel 3: gather segments into packed output + mask ----------------
// Block ro = b*T + r handles output row r of batch b (D=1024 floats, 256 thr x float4).
// Row r (< n_fires): leftover of previous fire + sum of cur_t * h_t through t_end.
// Row r (>= n_fires): zeros (d_out is poisoned).
__global__ __launch_bounds__(256) void gather_kernel(
    const float* __restrict__ hs, const float* __restrict__ alphas,
    const float* __restrict__ cur, const int* __restrict__ fire_times,
    const int* __restrict__ n_fires, const int* __restrict__ len_labels,
    float* __restrict__ out, float* __restrict__ out_mask)
{
    int ro = blockIdx.x;           // b*T + r
    int b  = ro >> 11;             // / TT
    int r  = ro & (TT - 1);
    if (threadIdx.x == 0)
        out_mask[ro] = (r < len_labels[b]) ? 1.f : 0.f;

    float4* op = (float4*)(out + (size_t)ro * DD);
    int ti = threadIdx.x;
    if (r >= n_fires[b]) {
        float4 z = {0.f, 0.f, 0.f, 0.f};
        op[ti] = z;
        return;
    }
    int t_end  = fire_times[b * TT + r];
    int t_prev = r ? fire_times[b * TT + r - 1] : -1;

    const float4* hsb = (const float4*)(hs + (size_t)b * TT * DD);
    float4 acc = {0.f, 0.f, 0.f, 0.f};
    if (t_prev >= 0) {
        // leftover from the previous fire: (alpha - cur) * h_{t_prev}
        float c = alphas[b * TT + t_prev] - cur[b * TT + t_prev];
        float4 h = hsb[(size_t)t_prev * 256 + ti];
        acc.x += c * h.x; acc.y += c * h.y; acc.z += c * h.z; acc.w += c * h.w;
    }
    for (int t = t_prev + 1; t <= t_end; ++t) {
        float c = cur[b * TT + t];     // broadcast load
        float4 h = hsb[(size_t)t * 256 + ti];
        acc.x += c * h.x; acc.y += c * h.y; acc.z += c * h.z; acc.w += c * h.w;
    }
    op[ti] = acc;
}

extern "C" void kernel_launch(void* const* d_in, const int* in_sizes, int n_in,
                              void* d_out, int out_size, void* d_ws, size_t ws_size,
                              hipStream_t stream) {
    const float* hs      = (const float*)d_in[0];   // [B,T,D]
    const float* hs_mask = (const float*)d_in[1];   // [B,1,T]
    const float* w       = (const float*)d_in[2];   // [D]
    const float* bias    = (const float*)d_in[3];   // scalar

    float* out      = (float*)d_out;                       // [B,T,D]
    float* out_mask = out + (size_t)BB * TT * DD;          // [B,1,T] as 0/1 floats

    float* alphas     = (float*)d_ws;                      // B*T floats
    float* cur        = alphas + BB * TT;                  // B*T floats
    int*   fire_times = (int*)(cur + BB * TT);             // B*T ints
    int*   n_fires    = fire_times + BB * TT;              // B ints
    int*   len_labels = n_fires + BB;                      // B ints

    proj_kernel<<<BB * TT / 4, 256, 0, stream>>>(hs, hs_mask, w, bias, alphas);
    scan_kernel<<<BB, 256, 0, stream>>>(alphas, cur, fire_times, n_fires, len_labels);
    gather_kernel<<<BB * TT, 256, 0, stream>>>(hs, alphas, cur, fire_times,
                                               n_fires, len_labels, out, out_mask);
}